// Round 3
// baseline (153266.516 us; speedup 1.0000x reference)
//
#include <hip/hip_runtime.h>

// ---------------------------------------------------------------------------
// RecurrentChannelAttentionV3: 3 LSTMs (K,V batch=5; Q batch=1, C=512, T=8192)
// + sequential channel-attention EMA scan.
// Phases: prep/convert -> per-chunk { Gx projection GEMM (fp16 MFMA) ->
// weight-stationary distributed LSTM recurrence (16 WGs/LSTM, flag barrier
// per step, c-state carried in ws across chunks) } -> qprime GEMM ->
// 4-WG feature-sliced attention scan.
// Chunking keeps the Gx staging buffers at ~46 MB (ws total ~209 MB).
// ---------------------------------------------------------------------------

typedef _Float16 f16;
typedef _Float16 f16x8 __attribute__((ext_vector_type(8)));
typedef float f32x4 __attribute__((ext_vector_type(4)));

#define SCOPE_AGENT __HIP_MEMORY_SCOPE_AGENT
#define TCH 1024          // time-chunk length
#define NCH 8             // 8192 / TCH
#define SPIN_MAX 50000000

__device__ __forceinline__ float sigm(float x){ return 1.0f/(1.0f + __expf(-x)); }
__device__ __forceinline__ float tanh_(float x){
  x = fminf(fmaxf(x, -15.0f), 15.0f);
  float e = __expf(2.0f*x);
  return (e-1.0f)/(e+1.0f);
}

// ---------------- prep kernels ----------------

__global__ void k_conv(const float* __restrict__ src, f16* __restrict__ dst, int n8){
  int i = blockIdx.x*blockDim.x + threadIdx.x;
  if (i >= n8) return;
  const float4* s4 = (const float4*)src;
  float4 a = s4[i*2], b = s4[i*2+1];
  f16x8 o = { (f16)a.x,(f16)a.y,(f16)a.z,(f16)a.w,(f16)b.x,(f16)b.y,(f16)b.z,(f16)b.w };
  *((f16x8*)dst + i) = o;
}

__global__ void k_zero(unsigned* __restrict__ p, int n){
  int i = blockIdx.x*blockDim.x + threadIdx.x;
  if (i < n) p[i] = 0u;
}

// permute Wih rows into slice-order jp = [s:4][w:2][gate:2][ul:3], convert f16,
// and build combined bias. gj = gate*512 + s*32 + w*8 + ul
__global__ void k_prep_wih(const float* __restrict__ wih, const float* __restrict__ bih,
                           const float* __restrict__ bhh, f16* __restrict__ wihp,
                           float* __restrict__ biasp){
  int jp = blockIdx.x;
  int ul = jp & 7, gate = (jp>>3)&3, wv = (jp>>5)&3, s = jp>>7;
  int gj = gate*512 + s*32 + wv*8 + ul;
  for (int k = threadIdx.x; k < 512; k += 128)
    wihp[(size_t)jp*512 + k] = (f16)wih[(size_t)gj*512 + k];
  if (threadIdx.x == 0) biasp[jp] = bih[gj] + bhh[gj];
}

__global__ void k_conv_weo(const float* __restrict__ we, f16* __restrict__ weo){
  int j = blockIdx.x;
  for (int c = threadIdx.x; c < 512; c += 256)
    weo[(size_t)j*512 + c] = (f16)we[(size_t)j*1024 + 512 + c];
}

__global__ void k_sentinel(float* out, float v){ out[0] = v; }

// ---------------- Gx projection GEMM (one T-chunk) ----------------
// Gx[tl][jp][b] (f16) = x[b,t0+tl,:] @ Wih_p[jp,:]^T + bias_p[jp]
// g=0: K (x, nb=5), g=1: V (x, nb=5), g=2: Q (y, nb=1)
__global__ __launch_bounds__(256,1) void k_proj(
    const f16* __restrict__ xh, const f16* __restrict__ yh,
    const f16* __restrict__ wihp_all, const float* __restrict__ biasp_all,
    f16* __restrict__ gk, f16* __restrict__ gv, f16* __restrict__ gq, int t0)
{
  int g = blockIdx.z;
  int ncols = (g==2) ? TCH : TCH*5;
  int cchunk = blockIdx.y;
  if (cchunk*256 >= ncols) return;
  int jchunk = blockIdx.x;
  int w = threadIdx.x>>6, l = threadIdx.x&63, hi = l>>4, c16 = l&15;
  const f16* W = wihp_all + (size_t)g*2048*512;
  const float* biasp = biasp_all + g*2048;
  const f16* B = (g==2) ? yh : xh;
  f16* out = (g==0) ? gk : (g==1 ? gv : gq);
  int nb = (g==2) ? 1 : 5;
  int jbase = jchunk*64 + w*16;

  f16x8 A[16];
  {
    const f16* ar = W + (size_t)(jbase + c16)*512 + hi*8;
    #pragma unroll
    for (int kk=0;kk<16;kk++) A[kk] = *(const f16x8*)(ar + kk*32);
  }
  float bias[4];
  #pragma unroll
  for (int r=0;r<4;r++) bias[r] = biasp[jbase + hi*4 + r];

  for (int ct=0; ct<16; ct++){
    int col = cchunk*256 + ct*16 + c16;
    int tl, b;
    if (g==2){ tl = col; b = 0; }
    else { tl = (int)(__umulhi((unsigned)col, 0xCCCCCCCDu) >> 2); b = col - tl*5; }
    const f16* bp = B + ((size_t)b*8192 + (t0 + tl))*512 + hi*8;
    f16x8 Bf[16];
    #pragma unroll
    for (int kk=0;kk<16;kk++) Bf[kk] = *(const f16x8*)(bp + kk*32);
    f32x4 acc = {0.f,0.f,0.f,0.f};
    #pragma unroll
    for (int kk=0;kk<16;kk++)
      acc = __builtin_amdgcn_mfma_f32_16x16x32_f16(A[kk], Bf[kk], acc, 0,0,0);
    #pragma unroll
    for (int r=0;r<4;r++){
      int jp = jbase + hi*4 + r;
      out[((size_t)tl*2048 + jp)*nb + b] = (f16)(acc[r] + bias[r]);
    }
  }
}

// ---------------- distributed LSTM recurrence (one T-chunk) ----------------
// grid 128: g = bid&7 (active g<3), s = bid>>3 (16 slices). 256 thr / 4 waves.
// Slice s owns 32 hidden units; wave w owns 8 units x 4 gates = 32 gate rows
// (2 MFMA jtiles: {i,f} and {g,o}). Whh A-fragments live in VGPRs.
// Per step: h all-gather via hbuf (device-scope), flag barrier across 16 WGs.
// Cell state c is carried across chunk launches via cst.
__global__ __launch_bounds__(256,1) void k_lstm(
    const f16* __restrict__ whh_all,
    const f16* __restrict__ gk, const f16* __restrict__ gv, const f16* __restrict__ gq,
    f16* __restrict__ hbuf, unsigned* __restrict__ flags,
    f16* __restrict__ kout, f16* __restrict__ vout, f16* __restrict__ qout,
    float* __restrict__ cst, int t0)
{
  int bid = blockIdx.x;
  int g = bid & 7;
  if (g >= 3) return;
  int s = bid >> 3;
  int w = threadIdx.x >> 6, l = threadIdx.x & 63, hi = l >> 4, b = l & 15;
  int nb = (g==2) ? 1 : 5;
  const f16* gx = (g==0) ? gk : (g==1 ? gv : gq);
  f16* outp = (g==0) ? kout : (g==1 ? vout : qout);
  const f16* whh = whh_all + (size_t)g*2048*512;
  f16* hb = hbuf + (size_t)g*(2*16*512);
  unsigned* fl = flags + g*16;

  // A fragments (Whh slice) -> VGPRs. Tile jt row (l&15): gate = jt*2+(b>>3), ul=b&7
  f16x8 A[2][16];
  #pragma unroll
  for (int jt=0;jt<2;jt++){
    int gate = jt*2 + (b>>3);
    int gj = gate*512 + s*32 + w*8 + (b&7);
    const f16* ar = whh + (size_t)gj*512 + hi*8;
    #pragma unroll
    for (int kk=0;kk<16;kk++) A[jt][kk] = *(const f16x8*)(ar + kk*32);
  }

  const bool valid = (b < nb);
  const bool lowh  = (hi < 2);
  const int jpb = (s*4 + w)*32;
  const int gu  = s*32 + w*8 + hi*4;

  float c_r[4] = {0.f,0.f,0.f,0.f};
  if (t0 > 0 && lowh && valid){
    const float4 cv = *(const float4*)&cst[(size_t)(g*5 + b)*512 + gu];
    c_r[0]=cv.x; c_r[1]=cv.y; c_r[2]=cv.z; c_r[3]=cv.w;
  }

  f16 gxc[8];
  #pragma unroll
  for (int jt=0;jt<2;jt++)
    #pragma unroll
    for (int r=0;r<4;r++)
      gxc[jt*4+r] = valid ? gx[((size_t)0*2048 + jpb + jt*16 + hi*4 + r)*nb + b] : (f16)0.f;

  for (int t=t0; t<t0+TCH; ++t){
    int tl = t - t0;
    // prefetch next step's Gx (HBM stream) before the barrier
    f16 gxn[8];
    if (tl+1 < TCH){
      #pragma unroll
      for (int jt=0;jt<2;jt++)
        #pragma unroll
        for (int r=0;r<4;r++)
          gxn[jt*4+r] = valid ? gx[((size_t)(tl+1)*2048 + jpb + jt*16 + hi*4 + r)*nb + b] : (f16)0.f;
    } else {
      #pragma unroll
      for (int r=0;r<8;r++) gxn[r] = (f16)0.f;
    }

    if (t > 0){
      bool ok; int spin = 0;
      do {
        unsigned fv = (l < 16) ? __hip_atomic_load(&fl[l], __ATOMIC_ACQUIRE, SCOPE_AGENT)
                               : 0xFFFFFFFFu;
        ok = (bool)__all((int)(fv >= (unsigned)t));
      } while (!ok && ++spin < SPIN_MAX);
    }

    // B fragments: h[b][k] from exchange buffer (device-scope loads)
    f16* hsrc = hb + (size_t)(t&1)*(16*512) + b*512 + hi*8;
    f16x8 Bf[16];
    #pragma unroll
    for (int kk=0;kk<16;kk++){
      union { unsigned long long q[2]; f16x8 v; } u;
      u.q[0] = __hip_atomic_load((unsigned long long*)(hsrc + kk*32),     __ATOMIC_RELAXED, SCOPE_AGENT);
      u.q[1] = __hip_atomic_load((unsigned long long*)(hsrc + kk*32 + 4), __ATOMIC_RELAXED, SCOPE_AGENT);
      Bf[kk] = u.v;
    }

    f32x4 acc0 = {0.f,0.f,0.f,0.f}, acc1 = {0.f,0.f,0.f,0.f};
    #pragma unroll
    for (int kk=0;kk<16;kk++){
      acc0 = __builtin_amdgcn_mfma_f32_16x16x32_f16(A[0][kk], Bf[kk], acc0, 0,0,0);
      acc1 = __builtin_amdgcn_mfma_f32_16x16x32_f16(A[1][kk], Bf[kk], acc1, 0,0,0);
    }

    float ga[4], gb2[4], gaX[4], gbX[4];
    #pragma unroll
    for (int r=0;r<4;r++){ ga[r]  = acc0[r] + (float)gxc[r];
                           gb2[r] = acc1[r] + (float)gxc[4+r]; }
    #pragma unroll
    for (int r=0;r<4;r++){ gaX[r] = __shfl_xor(ga[r], 32);
                           gbX[r] = __shfl_xor(gb2[r], 32); }

    if (lowh){
      // low-half lanes: i = ga, f = gaX, g = gb2, o = gbX ; unit u = gu+r
      f16 hh[4];
      #pragma unroll
      for (int r=0;r<4;r++){
        float ii = sigm(ga[r]),  ff = sigm(gaX[r]);
        float gg = tanh_(gb2[r]), oo = sigm(gbX[r]);
        float c = ff*c_r[r] + ii*gg;
        c_r[r] = c;
        hh[r] = (f16)(oo * tanh_(c));
      }
      if (valid){
        union { f16 h4[4]; unsigned long long q; } uh;
        uh.h4[0]=hh[0]; uh.h4[1]=hh[1]; uh.h4[2]=hh[2]; uh.h4[3]=hh[3];
        __hip_atomic_store((unsigned long long*)(hb + (size_t)((t+1)&1)*(16*512) + b*512 + gu),
                           uh.q, __ATOMIC_RELAXED, SCOPE_AGENT);
        *(unsigned long long*)(outp + ((size_t)t*nb + b)*512 + gu) = uh.q;
      }
    }

    __syncthreads();
    if (threadIdx.x == 0)
      __hip_atomic_store(&fl[s], (unsigned)(t+1), __ATOMIC_RELEASE, SCOPE_AGENT);

    #pragma unroll
    for (int r=0;r<8;r++) gxc[r] = gxn[r];
  }

  if (lowh && valid){
    float4 cv; cv.x=c_r[0]; cv.y=c_r[1]; cv.z=c_r[2]; cv.w=c_r[3];
    *(float4*)&cst[(size_t)(g*5 + b)*512 + gu] = cv;
  }
}

// ---------------- qprime = Q @ We[:, :512]^T + We_b ----------------
__global__ __launch_bounds__(256) void k_qprime(
    const f16* __restrict__ qh, const float* __restrict__ we,
    const float* __restrict__ web, float* __restrict__ qp)
{
  __shared__ float qt[512][17];
  int t0 = blockIdx.x * 16;
  for (int idx = threadIdx.x; idx < 8192; idx += 256){
    int tr = idx >> 9, k = idx & 511;
    qt[k][tr] = (float)qh[(size_t)(t0+tr)*512 + k];
  }
  __syncthreads();
  #pragma unroll
  for (int jj=0;jj<2;jj++){
    int j = threadIdx.x + jj*256;
    float bb = web[j];
    float acc[16];
    #pragma unroll
    for (int tr=0;tr<16;tr++) acc[tr] = bb;
    const float* wr = we + (size_t)j*1024;
    for (int k=0;k<512;k++){
      float wv = wr[k];
      #pragma unroll
      for (int tr=0;tr<16;tr++) acc[tr] += wv * qt[k][tr];
    }
    #pragma unroll
    for (int tr=0;tr<16;tr++) qp[(size_t)(t0+tr)*512 + j] = acc[tr];
  }
}

// ---------------- attention scan (4 WGs, feature-sliced) ----------------
__global__ __launch_bounds__(256,1) void k_attn(
    const f16* __restrict__ weo, const float* __restrict__ qp,
    const f16* __restrict__ kouth, const f16* __restrict__ vouth,
    float* __restrict__ dout,
    float* __restrict__ out_x, float* __restrict__ part_x,
    unsigned* __restrict__ flag_a, unsigned* __restrict__ flag_b)
{
  int wg = blockIdx.x;
  int tid = threadIdx.x;
  int w = tid>>6, l = tid&63, hi = l>>4, c16 = l&15;
  __shared__ __align__(16) f16 outh[512];
  __shared__ float qes[128];
  __shared__ float red[4];
  int F0 = wg*128;

  // We_o slice A-fragments in VGPRs
  f16x8 A[2][16];
  #pragma unroll
  for (int jt=0;jt<2;jt++){
    int j = F0 + w*32 + jt*16 + c16;
    const f16* ar = weo + (size_t)j*512 + hi*8;
    #pragma unroll
    for (int kk=0;kk<16;kk++) A[jt][kk] = *(const f16x8*)(ar + kk*32);
  }

  float s5[5] = {0.f,0.f,0.f,0.f,0.f};
  float mu = 0.f, p = 1.f;
  int f_g = F0 + tid; // meaningful for tid<128

  f16 vcur[5], kcur[5]; float qpc = 0.f;
  if (tid < 128){
    #pragma unroll
    for (int m=0;m<5;m++){ vcur[m] = vouth[(size_t)m*512 + f_g];
                           kcur[m] = kouth[(size_t)m*512 + f_g]; }
    qpc = qp[f_g];
  } else {
    #pragma unroll
    for (int m=0;m<5;m++){ vcur[m]=(f16)0.f; kcur[m]=(f16)0.f; }
  }

  for (int t=0;t<8192;++t){
    // prefetch next step's V/K/qprime
    f16 vnx[5], knx[5]; float qpn = 0.f;
    if (tid < 128 && t+1 < 8192){
      #pragma unroll
      for (int m=0;m<5;m++){
        vnx[m] = vouth[((size_t)(t+1)*5 + m)*512 + f_g];
        knx[m] = kouth[((size_t)(t+1)*5 + m)*512 + f_g];
      }
      qpn = qp[(size_t)(t+1)*512 + f_g];
    } else {
      #pragma unroll
      for (int m=0;m<5;m++){ vnx[m]=(f16)0.f; knx[m]=(f16)0.f; }
    }

    // phase A: out_t (uses att_{t-1} = mu * s) ; att_{-1} == ones
    if (tid < 128){
      float o;
      if (t == 0){
        o = (float)vcur[0]+(float)vcur[1]+(float)vcur[2]+(float)vcur[3]+(float)vcur[4];
      } else {
        float a = 0.f;
        #pragma unroll
        for (int m=0;m<5;m++) a += s5[m]*(float)vcur[m];
        o = mu*a;
      }
      dout[(size_t)t*512 + f_g] = o;
      __hip_atomic_store(&out_x[f_g], o, __ATOMIC_RELAXED, SCOPE_AGENT);
    }
    __syncthreads();
    if (tid == 0) __hip_atomic_store(&flag_a[wg], (unsigned)(t+1), __ATOMIC_RELEASE, SCOPE_AGENT);
    { bool ok; int spin = 0;
      do { unsigned fv = __hip_atomic_load(&flag_a[l&3], __ATOMIC_ACQUIRE, SCOPE_AGENT);
           ok = (bool)__all((int)(fv >= (unsigned)(t+1))); } while(!ok && ++spin < SPIN_MAX); }

    { int i0 = tid*2;
      float v0 = __hip_atomic_load(&out_x[i0],   __ATOMIC_RELAXED, SCOPE_AGENT);
      float v1 = __hip_atomic_load(&out_x[i0+1], __ATOMIC_RELAXED, SCOPE_AGENT);
      outh[i0] = (f16)v0; outh[i0+1] = (f16)v1; }
    __syncthreads();

    // phase B: qe slice = We_o[F,:] @ out (b-broadcast MFMA)
    f32x4 acc0 = {0.f,0.f,0.f,0.f}, acc1 = {0.f,0.f,0.f,0.f};
    #pragma unroll
    for (int kk=0;kk<16;kk++){
      f16x8 Bf = *(const f16x8*)(&outh[hi*8 + kk*32]);
      acc0 = __builtin_amdgcn_mfma_f32_16x16x32_f16(A[0][kk], Bf, acc0, 0,0,0);
      acc1 = __builtin_amdgcn_mfma_f32_16x16x32_f16(A[1][kk], Bf, acc1, 0,0,0);
    }
    if (c16 == 0){
      #pragma unroll
      for (int r=0;r<4;r++){
        qes[w*32 + hi*4 + r]      = acc0[r];
        qes[w*32 + 16 + hi*4 + r] = acc1[r];
      }
    }
    __syncthreads();

    float part = 0.f;
    if (tid < 128){
      float qe = qes[tid] + qpc;
      #pragma unroll
      for (int m=0;m<5;m++){
        float a = qe * (float)kcur[m];
        s5[m] = 0.95f*s5[m] + 0.05f*a;
        part += s5[m]*s5[m];
      }
    }
    #pragma unroll
    for (int off=32; off>0; off>>=1) part += __shfl_down(part, off);
    if (l == 0) red[w] = part;
    __syncthreads();
    if (tid == 0){
      float tot = red[0]+red[1]+red[2]+red[3];
      __hip_atomic_store(&part_x[wg], tot, __ATOMIC_RELAXED, SCOPE_AGENT);
      __hip_atomic_store(&flag_b[wg], (unsigned)(t+1), __ATOMIC_RELEASE, SCOPE_AGENT);
    }
    { bool ok; int spin = 0;
      do { unsigned fv = __hip_atomic_load(&flag_b[l&3], __ATOMIC_ACQUIRE, SCOPE_AGENT);
           ok = (bool)__all((int)(fv >= (unsigned)(t+1))); } while(!ok && ++spin < SPIN_MAX); }

    float tot = 0.f;
    #pragma unroll
    for (int q4=0;q4<4;q4++) tot += __hip_atomic_load(&part_x[q4], __ATOMIC_RELAXED, SCOPE_AGENT);
    p *= 0.95f;
    float bc = 1.0f - p;
    mu = 1.0f/(sqrtf(tot) + 1e-12f*bc);

    #pragma unroll
    for (int m=0;m<5;m++){ vcur[m]=vnx[m]; kcur[m]=knx[m]; }
    qpc = qpn;
  }
}

// ---------------- host ----------------

extern "C" void kernel_launch(void* const* d_in, const int* in_sizes, int n_in,
                              void* d_out, int out_size, void* d_ws, size_t ws_size,
                              hipStream_t stream)
{
  const float* x      = (const float*)d_in[0];
  const float* y      = (const float*)d_in[1];
  const float* wk_ih  = (const float*)d_in[2];
  const float* wk_hh  = (const float*)d_in[3];
  const float* wk_bih = (const float*)d_in[4];
  const float* wk_bhh = (const float*)d_in[5];
  const float* wq_ih  = (const float*)d_in[6];
  const float* wq_hh  = (const float*)d_in[7];
  const float* wq_bih = (const float*)d_in[8];
  const float* wq_bhh = (const float*)d_in[9];
  const float* wv_ih  = (const float*)d_in[10];
  const float* wv_hh  = (const float*)d_in[11];
  const float* wv_bih = (const float*)d_in[12];
  const float* wv_bhh = (const float*)d_in[13];
  const float* we_w   = (const float*)d_in[14];
  const float* we_b   = (const float*)d_in[15];
  float* out = (float*)d_out;

  char* ws = (char*)d_ws;
  size_t off = 0;
  auto alloc = [&](size_t bytes){ size_t o = off; off += (bytes + 255) & ~(size_t)255; return o; };
  const size_t oXH   = alloc(5ull*8192*512*2);      // 41.9 MB
  const size_t oYH   = alloc(8192ull*512*2);        //  8.4 MB
  const size_t oWHH  = alloc(3ull*2048*512*2);      //  6.3 MB
  const size_t oWIHP = alloc(3ull*2048*512*2);      //  6.3 MB
  const size_t oBIAS = alloc(3ull*2048*4);
  const size_t oWEO  = alloc(512ull*512*2);
  const size_t oGK   = alloc((size_t)TCH*2048*5*2); // 21.0 MB (chunked)
  const size_t oGV   = alloc((size_t)TCH*2048*5*2); // 21.0 MB
  const size_t oGQ   = alloc((size_t)TCH*2048*2);   //  4.2 MB
  const size_t oKOUT = alloc(8192ull*5*512*2);      // 41.9 MB
  const size_t oVOUT = alloc(8192ull*5*512*2);      // 41.9 MB
  const size_t oQOUT = alloc(8192ull*512*2);        //  8.4 MB
  const size_t oQP   = alloc(8192ull*512*4);        // 16.8 MB
  const size_t oCST  = alloc(3ull*5*512*4);         // 30.7 KB (c carry)
  const size_t oZ    = alloc(101376);
  // total ~209 MB

  if (off > ws_size){ k_sentinel<<<1,1,0,stream>>>(out, (float)ws_size); return; }

  f16* xh     = (f16*)(ws+oXH);
  f16* yh     = (f16*)(ws+oYH);
  f16* whh    = (f16*)(ws+oWHH);
  f16* wihp   = (f16*)(ws+oWIHP);
  float* bias = (float*)(ws+oBIAS);
  f16* weo    = (f16*)(ws+oWEO);
  f16* gkp    = (f16*)(ws+oGK);
  f16* gvp    = (f16*)(ws+oGV);
  f16* gqp    = (f16*)(ws+oGQ);
  f16* koutp  = (f16*)(ws+oKOUT);
  f16* voutp  = (f16*)(ws+oVOUT);
  f16* qoutp  = (f16*)(ws+oQOUT);
  float* qpp  = (float*)(ws+oQP);
  float* cst  = (float*)(ws+oCST);
  // zero region layout
  f16* hbuf       = (f16*)(ws+oZ);                 // 98304 B
  unsigned* flags = (unsigned*)(ws+oZ+98304);      // 192 B (padded to 256)
  float* out_x    = (float*)(ws+oZ+98560);         // 2048 B
  float* part_x   = (float*)(ws+oZ+100608);        // 16 B
  unsigned* flag_a = (unsigned*)(ws+oZ+100624);    // 16 B
  unsigned* flag_b = (unsigned*)(ws+oZ+100640);    // 16 B

  // 1) conversions
  { int n8 = 5*8192*512/8;  k_conv<<<(n8+255)/256,256,0,stream>>>(x, xh, n8); }
  { int n8 = 8192*512/8;    k_conv<<<(n8+255)/256,256,0,stream>>>(y, yh, n8); }
  { int n8 = 2048*512/8;
    k_conv<<<(n8+255)/256,256,0,stream>>>(wk_hh, whh,               n8);
    k_conv<<<(n8+255)/256,256,0,stream>>>(wv_hh, whh + 2048*512,    n8);
    k_conv<<<(n8+255)/256,256,0,stream>>>(wq_hh, whh + 2*2048*512,  n8); }
  k_prep_wih<<<2048,128,0,stream>>>(wk_ih, wk_bih, wk_bhh, wihp,              bias);
  k_prep_wih<<<2048,128,0,stream>>>(wv_ih, wv_bih, wv_bhh, wihp + 2048*512,   bias + 2048);
  k_prep_wih<<<2048,128,0,stream>>>(wq_ih, wq_bih, wq_bhh, wihp + 2*2048*512, bias + 2*2048);
  k_conv_weo<<<512,256,0,stream>>>(we_w, weo);
  { int nz = 101376/4; k_zero<<<(nz+255)/256,256,0,stream>>>((unsigned*)(ws+oZ), nz); }

  // 2+3) per-chunk: Gx projection GEMM, then LSTM recurrence over the chunk
  for (int ch = 0; ch < NCH; ++ch){
    k_proj<<<dim3(32,20,3),256,0,stream>>>(xh, yh, wihp, bias, gkp, gvp, gqp, ch*TCH);
    k_lstm<<<128,256,0,stream>>>(whh, gkp, gvp, gqp, hbuf, flags,
                                 koutp, voutp, qoutp, cst, ch*TCH);
  }

  // 4) qprime
  k_qprime<<<512,256,0,stream>>>(qoutp, we_w, we_b, qpp);

  // 5) attention scan
  k_attn<<<4,256,0,stream>>>(weo, qpp, koutp, voutp, out, out_x, part_x, flag_a, flag_b);
}

// Round 5
// 114173.865 us; speedup vs baseline: 1.3424x; 1.3424x over previous
//
#include <hip/hip_runtime.h>

// ---------------------------------------------------------------------------
// RecurrentChannelAttentionV3: 3 LSTMs (K,V batch=5; Q batch=1, C=512, T=8192)
// + sequential channel-attention EMA scan.
// r3/r4: de-atomicized data plane (plain vector stores/loads + agent fences;
// atomics only on 64B-padded flags), Gx packed to 16B/thread/step, attention
// single-barrier (u/partial packet exchange) with qprime folded into its MFMA
// (A = full We rows, K=1024), attention merged into the LSTM kernel (bids>=128)
// so it pipelines behind the LSTM recurrence. SPIN_MAX bounds disaster time.
// ---------------------------------------------------------------------------

typedef _Float16 f16;
typedef _Float16 f16x8 __attribute__((ext_vector_type(8)));
typedef float f32x4 __attribute__((ext_vector_type(4)));

#define SCOPE_AGENT __HIP_MEMORY_SCOPE_AGENT
#define TCH 1024          // time-chunk length
#define NCH 8             // 8192 / TCH
#define SPIN_MAX 20000000

__device__ __forceinline__ float sigm(float x){ return 1.0f/(1.0f + __expf(-x)); }
__device__ __forceinline__ float tanh_(float x){
  x = fminf(fmaxf(x, -15.0f), 15.0f);
  float e = __expf(2.0f*x);
  return (e-1.0f)/(e+1.0f);
}
__device__ __forceinline__ void fence_rel(){ __builtin_amdgcn_fence(__ATOMIC_RELEASE, "agent"); }
__device__ __forceinline__ void fence_acq(){ __builtin_amdgcn_fence(__ATOMIC_ACQUIRE, "agent"); }

// ---------------- prep kernels ----------------

__global__ void k_conv(const float* __restrict__ src, f16* __restrict__ dst, int n8){
  int i = blockIdx.x*blockDim.x + threadIdx.x;
  if (i >= n8) return;
  const float4* s4 = (const float4*)src;
  float4 a = s4[i*2], b = s4[i*2+1];
  f16x8 o = { (f16)a.x,(f16)a.y,(f16)a.z,(f16)a.w,(f16)b.x,(f16)b.y,(f16)b.z,(f16)b.w };
  *((f16x8*)dst + i) = o;
}

__global__ void k_zero(unsigned* __restrict__ p, int n){
  int i = blockIdx.x*blockDim.x + threadIdx.x;
  if (i < n) p[i] = 0u;
}

// permute Wih rows into slice-order jp = [s:4][w:2][jt:1][gate-half:1][ul:3],
// convert f16, and build combined bias. gj = gate*512 + s*32 + w*8 + ul
__global__ void k_prep_wih(const float* __restrict__ wih, const float* __restrict__ bih,
                           const float* __restrict__ bhh, f16* __restrict__ wihp,
                           float* __restrict__ biasp){
  int jp = blockIdx.x;
  int ul = jp & 7, gate = (jp>>3)&3, wv = (jp>>5)&3, s = jp>>7;
  int gj = gate*512 + s*32 + wv*8 + ul;
  for (int k = threadIdx.x; k < 512; k += 128)
    wihp[(size_t)jp*512 + k] = (f16)wih[(size_t)gj*512 + k];
  if (threadIdx.x == 0) biasp[jp] = bih[gj] + bhh[gj];
}

__global__ void k_sentinel(float* out, float v){ out[0] = v; }

// ---------------- Gx projection GEMM (one T-chunk) ----------------
// Packed output: Gx2[tl][pk][b][8] where pk=(s*4+w)*4+hi, 8 = jt*4+r (16B per
// LSTM thread-step). g=0: K (x, nb=5), g=1: V (x, nb=5), g=2: Q (y, nb=1)
__global__ __launch_bounds__(256,1) void k_proj(
    const f16* __restrict__ xh, const f16* __restrict__ yh,
    const f16* __restrict__ wihp_all, const float* __restrict__ biasp_all,
    f16* __restrict__ gk, f16* __restrict__ gv, f16* __restrict__ gq, int t0)
{
  int g = blockIdx.z;
  int ncols = (g==2) ? TCH : TCH*5;
  int cchunk = blockIdx.y;
  if (cchunk*256 >= ncols) return;
  int jchunk = blockIdx.x;
  int w = threadIdx.x>>6, l = threadIdx.x&63, hi = l>>4, c16 = l&15;
  const f16* W = wihp_all + (size_t)g*2048*512;
  const float* biasp = biasp_all + g*2048;
  const f16* B = (g==2) ? yh : xh;
  f16* out = (g==0) ? gk : (g==1 ? gv : gq);
  int nb = (g==2) ? 1 : 5;
  int jbase = jchunk*64 + w*16;
  // packed-destination decomposition
  int s2 = jchunk>>1;
  int w2 = (jchunk&1)*2 + (w>>1);
  int jt = w&1;
  int pk = (s2*4 + w2)*4 + hi;

  f16x8 A[16];
  {
    const f16* ar = W + (size_t)(jbase + c16)*512 + hi*8;
    #pragma unroll
    for (int kk=0;kk<16;kk++) A[kk] = *(const f16x8*)(ar + kk*32);
  }
  float bias[4];
  #pragma unroll
  for (int r=0;r<4;r++) bias[r] = biasp[jbase + hi*4 + r];

  for (int ct=0; ct<16; ct++){
    int col = cchunk*256 + ct*16 + c16;
    int tl, b;
    if (g==2){ tl = col; b = 0; }
    else { tl = (int)(__umulhi((unsigned)col, 0xCCCCCCCDu) >> 2); b = col - tl*5; }
    const f16* bp = B + ((size_t)b*8192 + (t0 + tl))*512 + hi*8;
    f16x8 Bf[16];
    #pragma unroll
    for (int kk=0;kk<16;kk++) Bf[kk] = *(const f16x8*)(bp + kk*32);
    f32x4 acc = {0.f,0.f,0.f,0.f};
    #pragma unroll
    for (int kk=0;kk<16;kk++)
      acc = __builtin_amdgcn_mfma_f32_16x16x32_f16(A[kk], Bf[kk], acc, 0,0,0);
    union { f16 h4[4]; unsigned long long q; } u;
    #pragma unroll
    for (int r=0;r<4;r++) u.h4[r] = (f16)(acc[r] + bias[r]);
    *(unsigned long long*)(out + ((size_t)(tl*256 + pk)*nb + b)*8 + jt*4) = u.q;
  }
}

// ---------------- fused scan: LSTM recurrence + attention (one T-chunk) -----
// grid 132. bid<128: LSTM role, g=bid&7 (g<3 active), s=bid>>3 (16 slices).
// bid>=128: attention role, wg=bid-128 (4 WGs, 128 features each).
// Flags are 64B-padded (stride 16 u32). Data exchanged with plain vector
// stores/loads bracketed by agent release/acquire fences.
__global__ __launch_bounds__(256,1) void k_scan(
    const f16* __restrict__ whh_all,
    const f16* __restrict__ gk, const f16* __restrict__ gv, const f16* __restrict__ gq,
    f16* __restrict__ hbuf, unsigned* __restrict__ flags,
    f16* __restrict__ kout, f16* __restrict__ vout, f16* __restrict__ qout,
    float* __restrict__ cst,
    const f16* __restrict__ wecat, const float* __restrict__ web,
    float* __restrict__ sst, f16* __restrict__ ubuf, float* __restrict__ pbuf,
    unsigned* __restrict__ aflg, float* __restrict__ dout, int t0)
{
  int bid = blockIdx.x;
  int tid = threadIdx.x;
  int w = tid>>6, l = tid&63, hi = l>>4;

  if (bid < 128){
    // ================= LSTM role =================
    int g = bid & 7;
    if (g >= 3) return;
    int s = bid >> 3;
    int b = l & 15;
    int nb = (g==2) ? 1 : 5;
    const f16* gx = (g==0) ? gk : (g==1 ? gv : gq);
    f16* outp = (g==0) ? kout : (g==1 ? vout : qout);
    const f16* whh = whh_all + (size_t)g*2048*512;
    f16* hb = hbuf + (size_t)g*(2*16*512);
    unsigned* fl = flags + g*16*16;   // 64B-padded entries

    // A fragments (Whh slice) -> VGPRs
    f16x8 A[2][16];
    #pragma unroll
    for (int jt=0;jt<2;jt++){
      int gate = jt*2 + (b>>3);
      int gj = gate*512 + s*32 + w*8 + (b&7);
      const f16* ar = whh + (size_t)gj*512 + hi*8;
      #pragma unroll
      for (int kk=0;kk<16;kk++) A[jt][kk] = *(const f16x8*)(ar + kk*32);
    }

    const bool valid = (b < nb);
    const bool lowh  = (hi < 2);
    const int gu  = s*32 + w*8 + hi*4;
    const int pk  = (s*4 + w)*4 + hi;

    float c_r[4] = {0.f,0.f,0.f,0.f};
    if (t0 > 0 && lowh && valid){
      const float4 cv = *(const float4*)&cst[(size_t)(g*5 + b)*512 + gu];
      c_r[0]=cv.x; c_r[1]=cv.y; c_r[2]=cv.z; c_r[3]=cv.w;
    }

    f16x8 zero8 = {(f16)0.f,(f16)0.f,(f16)0.f,(f16)0.f,(f16)0.f,(f16)0.f,(f16)0.f,(f16)0.f};
    f16x8 gxc = valid ? *(const f16x8*)(gx + ((size_t)(0*256 + pk)*nb + b)*8) : zero8;

    for (int t=t0; t<t0+TCH; ++t){
      int tl = t - t0;
      // prefetch next step's packed Gx (single 16B load)
      f16x8 gxn = (valid && tl+1 < TCH)
                    ? *(const f16x8*)(gx + ((size_t)((tl+1)*256 + pk)*nb + b)*8) : zero8;

      if (t > 0){
        bool ok; int spin = 0;
        do {
          unsigned fv = (l < 16) ? __hip_atomic_load(&fl[l*16], __ATOMIC_RELAXED, SCOPE_AGENT)
                                 : 0xFFFFFFFFu;
          ok = (bool)__all((int)(fv >= (unsigned)t));
        } while (!ok && ++spin < SPIN_MAX);
        fence_acq();
      }

      // B fragments: plain vector loads (post-acquire)
      const f16* hsrc = hb + (size_t)(t&1)*(16*512) + b*512 + hi*8;
      f16x8 Bf[16];
      #pragma unroll
      for (int kk=0;kk<16;kk++) Bf[kk] = *(const f16x8*)(hsrc + kk*32);

      f32x4 acc0 = {0.f,0.f,0.f,0.f}, acc1 = {0.f,0.f,0.f,0.f};
      #pragma unroll
      for (int kk=0;kk<16;kk++){
        acc0 = __builtin_amdgcn_mfma_f32_16x16x32_f16(A[0][kk], Bf[kk], acc0, 0,0,0);
        acc1 = __builtin_amdgcn_mfma_f32_16x16x32_f16(A[1][kk], Bf[kk], acc1, 0,0,0);
      }

      float ga[4], gb2[4], gaX[4], gbX[4];
      #pragma unroll
      for (int r=0;r<4;r++){ ga[r]  = acc0[r] + (float)gxc[r];
                             gb2[r] = acc1[r] + (float)gxc[4+r]; }
      #pragma unroll
      for (int r=0;r<4;r++){ gaX[r] = __shfl_xor(ga[r], 32);
                             gbX[r] = __shfl_xor(gb2[r], 32); }

      if (lowh){
        f16 hh[4];
        #pragma unroll
        for (int r=0;r<4;r++){
          float ii = sigm(ga[r]),  ff = sigm(gaX[r]);
          float gg = tanh_(gb2[r]), oo = sigm(gbX[r]);
          float c = ff*c_r[r] + ii*gg;
          c_r[r] = c;
          hh[r] = (f16)(oo * tanh_(c));
        }
        if (valid){
          union { f16 h4[4]; unsigned long long q; } uh;
          uh.h4[0]=hh[0]; uh.h4[1]=hh[1]; uh.h4[2]=hh[2]; uh.h4[3]=hh[3];
          *(unsigned long long*)(hb + (size_t)((t+1)&1)*(16*512) + b*512 + gu) = uh.q;
          *(unsigned long long*)(outp + ((size_t)t*nb + b)*512 + gu) = uh.q;
        }
      }

      __syncthreads();   // drains each wave's vmcnt before barrier
      if (tid == 0){
        fence_rel();
        __hip_atomic_store(&fl[s*16], (unsigned)(t+1), __ATOMIC_RELAXED, SCOPE_AGENT);
      }
      gxc = gxn;
    }

    if (lowh && valid){
      float4 cv; cv.x=c_r[0]; cv.y=c_r[1]; cv.z=c_r[2]; cv.w=c_r[3];
      *(float4*)&cst[(size_t)(g*5 + b)*512 + gu] = cv;
    }

  } else {
    // ================= attention role =================
    int wg = bid - 128;
    if (wg >= 4) return;
    int c16 = l & 15;
    int F0 = wg*128;
    __shared__ float qes[128];
    __shared__ float red4[4];

    // A fragments: full We rows (K = 1024 = [q(512); u(512)])
    f16x8 A[2][32];
    #pragma unroll
    for (int jt=0;jt<2;jt++){
      int row = F0 + w*32 + jt*16 + c16;
      const f16* ar = wecat + (size_t)row*1024 + hi*8;
      #pragma unroll
      for (int kk=0;kk<32;kk++) A[jt][kk] = *(const f16x8*)(ar + kk*32);
    }
    float webr[2][4];
    #pragma unroll
    for (int jt=0;jt<2;jt++)
      #pragma unroll
      for (int r=0;r<4;r++) webr[jt][r] = web[F0 + w*32 + jt*16 + hi*4 + r];

    float s5[5] = {0.f,0.f,0.f,0.f,0.f};
    if (t0 > 0 && tid < 128){
      #pragma unroll
      for (int m=0;m<5;m++) s5[m] = sst[(size_t)(wg*128 + tid)*5 + m];
    }
    // partial_prev = sum over features of ||s||^2 (recomputed at launch entry)
    float partial_prev;
    {
      float part = 0.f;
      if (tid < 128){
        #pragma unroll
        for (int m=0;m<5;m++) part += s5[m]*s5[m];
      }
      #pragma unroll
      for (int off=32; off>0; off>>=1) part += __shfl_down(part, off);
      if (l == 0) red4[w] = part;
      __syncthreads();
      partial_prev = red4[0]+red4[1]+red4[2]+red4[3];
      __syncthreads();
    }
    float pw = __powf(0.95f, (float)t0);   // 0.95^t (t = current step)

    for (int t=t0; t<t0+TCH; ++t){
      // 1) wait for LSTM step t outputs (flags are monotone across launches)
      { bool ok; int spin = 0;
        do {
          unsigned fv = (l < 48) ? __hip_atomic_load(&flags[l*16], __ATOMIC_RELAXED, SCOPE_AGENT)
                                 : 0xFFFFFFFFu;
          ok = (bool)__all((int)(fv >= (unsigned)(t+1)));
        } while (!ok && ++spin < SPIN_MAX);
        fence_acq(); }

      // 2) load k_t, v_t (own features), q_t fragments (broadcast)
      float kc[5], vc[5];
      if (tid < 128){
        #pragma unroll
        for (int m=0;m<5;m++){
          kc[m] = (float)kout[((size_t)t*5 + m)*512 + F0 + tid];
          vc[m] = (float)vout[((size_t)t*5 + m)*512 + F0 + tid];
        }
      } else {
        #pragma unroll
        for (int m=0;m<5;m++){ kc[m]=0.f; vc[m]=0.f; }
      }
      f16x8 Bq[16];
      {
        const f16* qb = qout + (size_t)t*512 + hi*8;
        #pragma unroll
        for (int kk=0;kk<16;kk++) Bq[kk] = *(const f16x8*)(qb + kk*32);
      }

      // 3) acc_q = We_q @ q_t (independent of the packet barrier)
      f32x4 aq0 = {0.f,0.f,0.f,0.f}, aq1 = {0.f,0.f,0.f,0.f};
      #pragma unroll
      for (int kk=0;kk<16;kk++){
        aq0 = __builtin_amdgcn_mfma_f32_16x16x32_f16(A[0][kk], Bq[kk], aq0, 0,0,0);
        aq1 = __builtin_amdgcn_mfma_f32_16x16x32_f16(A[1][kk], Bq[kk], aq1, 0,0,0);
      }

      // 4) u_t = s_{t-1} . v_t (unscaled out); t=0: att=ones -> u = sum v
      float uval = 0.f;
      if (tid < 128){
        if (t == 0){ uval = vc[0]+vc[1]+vc[2]+vc[3]+vc[4]; }
        else {
          #pragma unroll
          for (int m=0;m<5;m++) uval += s5[m]*vc[m];
        }
      }

      // 5) publish packet {u_t slice, partial_{t-1}}
      if (tid < 128) ubuf[(size_t)(t&1)*512 + F0 + tid] = (f16)uval;
      if (tid == 0)  pbuf[((t&1)*4 + wg)*16] = partial_prev;
      __syncthreads();
      if (tid == 0){
        fence_rel();
        __hip_atomic_store(&aflg[wg*16], (unsigned)(t+1), __ATOMIC_RELAXED, SCOPE_AGENT);
      }

      // 6) wait all packets_t
      { bool ok; int spin = 0;
        do {
          unsigned fv = __hip_atomic_load(&aflg[(l&3)*16], __ATOMIC_RELAXED, SCOPE_AGENT);
          ok = (bool)__all((int)(fv >= (unsigned)(t+1)));
        } while (!ok && ++spin < SPIN_MAX);
        fence_acq(); }

      // 7) total norm partial (step t-1) -> mu_{t-1}
      float tot = pbuf[((t&1)*4 + 0)*16] + pbuf[((t&1)*4 + 1)*16]
                + pbuf[((t&1)*4 + 2)*16] + pbuf[((t&1)*4 + 3)*16];
      float mu = (t == 0) ? 1.0f : 1.0f/(sqrtf(tot) + 1e-12f*(1.0f - pw));

      // 8) acc_u = We_o @ u_t
      f32x4 au0 = {0.f,0.f,0.f,0.f}, au1 = {0.f,0.f,0.f,0.f};
      {
        const f16* ub = ubuf + (size_t)(t&1)*512 + hi*8;
        #pragma unroll
        for (int kk=16;kk<32;kk++){
          f16x8 Bu = *(const f16x8*)(ub + (kk-16)*32);
          au0 = __builtin_amdgcn_mfma_f32_16x16x32_f16(A[0][kk], Bu, au0, 0,0,0);
          au1 = __builtin_amdgcn_mfma_f32_16x16x32_f16(A[1][kk], Bu, au1, 0,0,0);
        }
      }

      // 9) qe rows -> LDS (qe = We_q@q + mu*We_o@u + web)
      if (c16 == 0){
        #pragma unroll
        for (int r=0;r<4;r++){
          qes[w*32 + hi*4 + r]      = aq0[r] + mu*au0[r] + webr[0][r];
          qes[w*32 + 16 + hi*4 + r] = aq1[r] + mu*au1[r] + webr[1][r];
        }
      }
      // 10) output
      if (tid < 128) dout[(size_t)t*512 + F0 + tid] = mu*uval;
      __syncthreads();

      // 11) s-EMA update + next norm partial
      float part = 0.f;
      if (tid < 128){
        float qe = qes[tid];
        #pragma unroll
        for (int m=0;m<5;m++){
          float a = qe * kc[m];
          s5[m] = 0.95f*s5[m] + 0.05f*a;
          part += s5[m]*s5[m];
        }
      }
      #pragma unroll
      for (int off=32; off>0; off>>=1) part += __shfl_down(part, off);
      if (l == 0) red4[w] = part;
      __syncthreads();
      partial_prev = red4[0]+red4[1]+red4[2]+red4[3];
      pw *= 0.95f;
    }

    if (tid < 128){
      #pragma unroll
      for (int m=0;m<5;m++) sst[(size_t)(wg*128 + tid)*5 + m] = s5[m];
    }
  }
}

// ---------------- host ----------------

extern "C" void kernel_launch(void* const* d_in, const int* in_sizes, int n_in,
                              void* d_out, int out_size, void* d_ws, size_t ws_size,
                              hipStream_t stream)
{
  const float* x      = (const float*)d_in[0];
  const float* y      = (const float*)d_in[1];
  const float* wk_ih  = (const float*)d_in[2];
  const float* wk_hh  = (const float*)d_in[3];
  const float* wk_bih = (const float*)d_in[4];
  const float* wk_bhh = (const float*)d_in[5];
  const float* wq_ih  = (const float*)d_in[6];
  const float* wq_hh  = (const float*)d_in[7];
  const float* wq_bih = (const float*)d_in[8];
  const float* wq_bhh = (const float*)d_in[9];
  const float* wv_ih  = (const float*)d_in[10];
  const float* wv_hh  = (const float*)d_in[11];
  const float* wv_bih = (const float*)d_in[12];
  const float* wv_bhh = (const float*)d_in[13];
  const float* we_w   = (const float*)d_in[14];
  const float* we_b   = (const float*)d_in[15];
  float* out = (float*)d_out;

  char* ws = (char*)d_ws;
  size_t off = 0;
  auto alloc = [&](size_t bytes){ size_t o = off; off += (bytes + 255) & ~(size_t)255; return o; };
  const size_t oXH   = alloc(5ull*8192*512*2);        // 41.9 MB
  const size_t oYH   = alloc(8192ull*512*2);          //  8.4 MB
  const size_t oWHH  = alloc(3ull*2048*512*2);        //  6.3 MB
  const size_t oWIHP = alloc(3ull*2048*512*2);        //  6.3 MB
  const size_t oBIAS = alloc(3ull*2048*4);
  const size_t oWE   = alloc(512ull*1024*2);          //  1.0 MB (full We, f16)
  const size_t oGK   = alloc((size_t)TCH*256*5*8*2);  // 21.0 MB (packed, chunked)
  const size_t oGV   = alloc((size_t)TCH*256*5*8*2);  // 21.0 MB
  const size_t oGQ   = alloc((size_t)TCH*256*8*2);    //  4.2 MB
  const size_t oKOUT = alloc(8192ull*5*512*2);        // 41.9 MB
  const size_t oVOUT = alloc(8192ull*5*512*2);        // 41.9 MB
  const size_t oQOUT = alloc(8192ull*512*2);          //  8.4 MB
  const size_t oCST  = alloc(3ull*5*512*4);           // c carry
  const size_t oSST  = alloc(4ull*128*5*4);           // attn s carry
  const size_t oZ    = alloc(104448);                 // zeroed region
  // total ~203 MB

  if (off > ws_size){ k_sentinel<<<1,1,0,stream>>>(out, (float)ws_size); return; }

  f16* xh     = (f16*)(ws+oXH);
  f16* yh     = (f16*)(ws+oYH);
  f16* whh    = (f16*)(ws+oWHH);
  f16* wihp   = (f16*)(ws+oWIHP);
  float* bias = (float*)(ws+oBIAS);
  f16* wecat  = (f16*)(ws+oWE);
  f16* gkp    = (f16*)(ws+oGK);
  f16* gvp    = (f16*)(ws+oGV);
  f16* gqp    = (f16*)(ws+oGQ);
  f16* koutp  = (f16*)(ws+oKOUT);
  f16* voutp  = (f16*)(ws+oVOUT);
  f16* qoutp  = (f16*)(ws+oQOUT);
  float* cst  = (float*)(ws+oCST);
  float* sst  = (float*)(ws+oSST);
  // zero region layout (all flag entries 64B-padded)
  f16* hbuf       = (f16*)(ws+oZ);                 // 98304 B
  unsigned* flags = (unsigned*)(ws+oZ+98304);      // 48*64 = 3072 B
  f16* ubuf       = (f16*)(ws+oZ+101376);          // 2*512*2 = 2048 B
  float* pbuf     = (float*)(ws+oZ+103424);        // 8*64 = 512 B
  unsigned* aflg  = (unsigned*)(ws+oZ+103936);     // 4*64 = 256 B

  // 1) conversions / weight prep
  { int n8 = 5*8192*512/8;  k_conv<<<(n8+255)/256,256,0,stream>>>(x, xh, n8); }
  { int n8 = 8192*512/8;    k_conv<<<(n8+255)/256,256,0,stream>>>(y, yh, n8); }
  { int n8 = 2048*512/8;
    k_conv<<<(n8+255)/256,256,0,stream>>>(wk_hh, whh,               n8);
    k_conv<<<(n8+255)/256,256,0,stream>>>(wv_hh, whh + 2048*512,    n8);
    k_conv<<<(n8+255)/256,256,0,stream>>>(wq_hh, whh + 2*2048*512,  n8); }
  { int n8 = 512*1024/8;    k_conv<<<(n8+255)/256,256,0,stream>>>(we_w, wecat, n8); }
  k_prep_wih<<<2048,128,0,stream>>>(wk_ih, wk_bih, wk_bhh, wihp,              bias);
  k_prep_wih<<<2048,128,0,stream>>>(wv_ih, wv_bih, wv_bhh, wihp + 2048*512,   bias + 2048);
  k_prep_wih<<<2048,128,0,stream>>>(wq_ih, wq_bih, wq_bhh, wihp + 2*2048*512, bias + 2*2048);
  { int nz = 104448/4; k_zero<<<(nz+255)/256,256,0,stream>>>((unsigned*)(ws+oZ), nz); }

  // 2) per-chunk: Gx projection GEMM, then fused LSTM+attention scan
  for (int ch = 0; ch < NCH; ++ch){
    k_proj<<<dim3(32,20,3),256,0,stream>>>(xh, yh, wihp, bias, gkp, gvp, gqp, ch*TCH);
    k_scan<<<132,256,0,stream>>>(whh, gkp, gvp, gqp, hbuf, flags,
                                 koutp, voutp, qoutp, cst,
                                 wecat, we_b, sst, ubuf, pbuf, aflg, out, ch*TCH);
  }
}